// Round 16
// baseline (76.191 us; speedup 1.0000x reference)
//
#include <hip/hip_runtime.h>
#include <hip/hip_bf16.h>
#include <type_traits>

#define DI __device__ __forceinline__

typedef unsigned short u16;
typedef unsigned int u32;
typedef __bf16 bf16x8 __attribute__((ext_vector_type(8)));
typedef u16 u16x8 __attribute__((ext_vector_type(8)));
typedef float f32x4 __attribute__((ext_vector_type(4)));
typedef float f32x16 __attribute__((ext_vector_type(16)));
typedef u32 u32x2 __attribute__((ext_vector_type(2)));
typedef u32 u32x4 __attribute__((ext_vector_type(4)));

constexpr int Bb = 2, Ls = 2048, Hh = 16, KVh = 4, HD = 64;
constexpr float LOG2E = 1.44269504088896f;
constexpr float RSQ2 = 0.70710678118654752f;   // slope ratio between heads

DI u16 f2bf(float f) {
  __hip_bfloat16 h = __float2bfloat16(f);
  return __builtin_bit_cast(u16, h);
}

// packed f32x2 -> bf16x2 (RNE), single VOP3 op
DI u32 cvtpk(float lo, float hi) {
  u32 r;
  asm("v_cvt_pk_bf16_f32 %0, %1, %2" : "=v"(r) : "v"(lo), "v"(hi));
  return r;
}

// a' = [a.lo | b.lo], b' = [a.hi | b.hi].  "&" early-clobber on b forces
// DISTINCT registers (r12 NaN landmine: equal-valued a,b coalesced into one
// reg -> swap(v0,v0) garbage).
DI void pls(u32& a, u32& b) {
  asm("v_permlane32_swap_b32 %0, %1" : "+v"(a), "+&v"(b));
}
DI float sum_halves(float v) {        // v[l] + v[l^32], valid in all lanes
  u32 a = __builtin_bit_cast(u32, v), b = a;
  pls(a, b);
  return __builtin_bit_cast(float, a) + __builtin_bit_cast(float, b);
}
DI float max_halves(float v) {
  u32 a = __builtin_bit_cast(u32, v), b = a;
  pls(a, b);
  return fmaxf(__builtin_bit_cast(float, a), __builtin_bit_cast(float, b));
}

DI f32x4 mfma16(bf16x8 a, bf16x8 b, f32x4 c) {
  return __builtin_amdgcn_mfma_f32_16x16x32_bf16(a, b, c, 0, 0, 0);
}
DI f32x16 mfma32(bf16x8 a, bf16x8 b, f32x16 c) {
  return __builtin_amdgcn_mfma_f32_32x32x16_bf16(a, b, c, 0, 0, 0);
}
DI bf16x8 bc(u32x4 v) { return __builtin_bit_cast(bf16x8, v); }

// async global->LDS, 16B per lane; LDS dest = wave-uniform base + lane*16
DI void gld16(const u16* g, u16* l) {
  __builtin_amdgcn_global_load_lds(
      (const __attribute__((address_space(1))) u32*)g,
      (__attribute__((address_space(3))) u32*)l, 16, 0, 0);
}

template <int N>
DI void waitvm() {
  asm volatile("s_waitcnt vmcnt(%0)" :: "i"(N) : "memory");
}

// ---- fused prep: hs cvt + seg starts + all 4 weight transposes -----------
__global__ void prep(const float* __restrict__ hs, u16* __restrict__ hsb,
                     const int* __restrict__ seg, int* __restrict__ sst,
                     const float* __restrict__ Wq, const float* __restrict__ Wk,
                     const float* __restrict__ Wv, const float* __restrict__ Wo,
                     u16* __restrict__ wqkvT, u16* __restrict__ woT) {
  int bid = blockIdx.x;
  if (bid < 4096) {
    int i = bid * 256 + threadIdx.x;
    float4 v = reinterpret_cast<const float4*>(hs)[i];
    ushort4 o;
    o.x = f2bf(v.x); o.y = f2bf(v.y); o.z = f2bf(v.z); o.w = f2bf(v.w);
    reinterpret_cast<ushort4*>(hsb)[i] = o;
    return;
  }
  if (bid < 4112) {
    int idx = bid - 4096;
    int b = idx >> 3;
    int l = (idx & 7) * 256 + threadIdx.x;
    const int* s = seg + b * Ls;
    int v = s[l];
    int lo = 0, hi = l;
    while (lo < hi) {
      int mid = (lo + hi) >> 1;
      if (s[mid] < v) lo = mid + 1; else hi = mid;
    }
    sst[b * Ls + l] = lo;
    return;
  }
  int t = bid - 4112;
  const float* in; u16* out; int N, rowoff, x, y;
  if (t < 1024)      { in = Wq; out = wqkvT; N = 1024; rowoff = 0;
                       x = t & 31; y = t >> 5; }
  else if (t < 1280) { in = Wk; out = wqkvT; N = 256; rowoff = 1024;
                       int u = t - 1024; x = u & 7; y = u >> 3; }
  else if (t < 1536) { in = Wv; out = wqkvT; N = 256; rowoff = 1280;
                       int u = t - 1280; x = u & 7; y = u >> 3; }
  else               { in = Wo; out = woT; N = 1024; rowoff = 0;
                       int u = t - 1536; x = u & 31; y = u >> 5; }
  __shared__ u16 tl[32][33];
  int k0 = y * 32, n0 = x * 32;
  int tx = threadIdx.x & 31, ty = threadIdx.x >> 5;
#pragma unroll
  for (int i = ty; i < 32; i += 8)
    tl[i][tx] = f2bf(in[(size_t)(k0 + i) * N + n0 + tx]);
  __syncthreads();
#pragma unroll
  for (int i = ty; i < 32; i += 8)
    out[(size_t)(rowoff + n0 + i) * 1024 + k0 + tx] = tl[tx][i];
}

// ---- GEMM: 128x128 tile, 4-buffer rotation, 1 barrier/K-step -------------
// NT=512: 8 waves (2Mx4N, 64x32 wave tile), 1 gld16/matrix/stage, vm 4/4/2/0.
// NT=256: 4 waves (2Mx2N, 64x64 wave tile), 2 gld16/matrix/stage, vm 8/8/4/0.
//   NT=256 halves LDS-read duplication (48->32KB per K-step) -> balanced
//   with the CU matrix pipe (~256cy each).
// Hardened barrier: lgkmcnt(0)+sched_barrier(0) before s_barrier (rule-18).
// LDS XOR swizzle both-sides (r11). Requires K % 128 == 0.
template <int MODE, int NT>
__global__ __launch_bounds__(NT) void gemm_bt(
    const u16* __restrict__ A, const u16* __restrict__ Bt,
    float* __restrict__ C, u16* __restrict__ Qf, u16* __restrict__ Kf,
    u16* __restrict__ Vf, int M, int N, int K) {
  constexpr int NREG = (NT == 512) ? 2 : 4;     // n-frags per wave
  __shared__ u16 lA[4][128 * 32];
  __shared__ u16 lB[4][128 * 32];
  const int m0 = blockIdx.y * 128, n0 = blockIdx.x * 128;
  const int tid = threadIdx.x;
  const int lane = tid & 63;
  const int wr = (NT == 512) ? ((tid >> 8) & 1) * 64 : ((tid >> 7) & 1) * 64;
  const int wc = (NT == 512) ? ((tid >> 6) & 3) * 32 : ((tid >> 6) & 1) * 64;
  const int lr = lane & 15;
  const int lk = (((lane >> 4) ^ (lane & 3)) * 8);     // swizzled read slot
  const int r0 = tid >> 2;
  const int c0 = (((tid & 3) ^ ((tid >> 2) & 3)) * 8); // swizzled src group
  constexpr int WMASK = (NT == 512) ? 0x1C0 : 0xC0;
  const int woff = (tid & WMASK) << 4;          // wave-uniform LDS byte base
  const u16* pA0 = &A[(size_t)(m0 + r0) * K + c0];
  const u16* pB0 = &Bt[(size_t)(n0 + r0) * K + c0];
  const u16* pA1 = &A[(size_t)(m0 + r0 + 64) * K + c0];   // NT=256 only
  const u16* pB1 = &Bt[(size_t)(n0 + r0 + 64) * K + c0];

  auto stage = [&](u16* sA, u16* sB, int k0) {
    if constexpr (NT == 512) {
      gld16(pA0 + k0, (u16*)((char*)sA + woff));
      gld16(pB0 + k0, (u16*)((char*)sB + woff));
    } else {
      gld16(pA0 + k0, (u16*)((char*)sA + woff));
      gld16(pA1 + k0, (u16*)((char*)sA + 4096 + woff));
      gld16(pB0 + k0, (u16*)((char*)sB + woff));
      gld16(pB1 + k0, (u16*)((char*)sB + 4096 + woff));
    }
  };

  f32x4 acc[4][NREG] = {};
  auto compute = [&](const u16* sA, const u16* sB) {
    bf16x8 af[4], bfv[NREG];
#pragma unroll
    for (int m = 0; m < 4; m++)
      af[m] = *reinterpret_cast<const bf16x8*>(&sA[(wr + m * 16 + lr) * 32 + lk]);
#pragma unroll
    for (int n = 0; n < NREG; n++)
      bfv[n] = *reinterpret_cast<const bf16x8*>(&sB[(wc + n * 16 + lr) * 32 + lk]);
#pragma unroll
    for (int m = 0; m < 4; m++)
#pragma unroll
      for (int n = 0; n < NREG; n++)
        acc[m][n] = mfma16(af[m], bfv[n], acc[m][n]);
  };

  constexpr int L2X = (NT == 512) ? 4 : 8;      // 2 stages in flight
  constexpr int L1X = (NT == 512) ? 2 : 4;      // 1 stage in flight

#define BODY(B, VM, KC, DOST)                                        \
  do {                                                               \
    asm volatile("s_waitcnt lgkmcnt(0)" ::: "memory");               \
    __builtin_amdgcn_sched_barrier(0);                               \
    waitvm<VM>();                                                    \
    __builtin_amdgcn_s_barrier();                                    \
    asm volatile("" ::: "memory");                                   \
    if (DOST) stage(lA[(B + 3) & 3], lB[(B + 3) & 3], (KC) + 96);    \
    compute(lA[B], lB[B]);                                           \
  } while (0)

  stage(lA[0], lB[0], 0);
  stage(lA[1], lB[1], 32);
  stage(lA[2], lB[2], 64);
  int k0 = 0;
  for (; k0 + 224 <= K; k0 += 128) {            // full groups, all stage
    BODY(0, L2X, k0, 1);
    BODY(1, L2X, k0 + 32, 1);
    BODY(2, L2X, k0 + 64, 1);
    BODY(3, L2X, k0 + 96, 1);
  }
  BODY(0, L2X, k0, 1);                          // stages K-32
  BODY(1, L2X, k0 + 32, 0);
  BODY(2, L1X, k0 + 64, 0);
  BODY(3, 0, k0 + 96, 0);
#undef BODY

  const int rr = (lane >> 4) * 4, cc = lane & 15;
#pragma unroll
  for (int m = 0; m < 4; m++) {
    int row0 = m0 + wr + m * 16 + rr;
#pragma unroll
    for (int n = 0; n < NREG; n++) {
      int col = n0 + wc + n * 16 + cc;
      if constexpr (MODE == 0) {
#pragma unroll
        for (int r = 0; r < 4; r++)
          C[(size_t)(row0 + r) * N + col] = acc[m][n][r];
      } else {
        int bb = row0 >> 11, l = row0 & 2047;
        int d = col & 63, c8 = d >> 3, d7 = d & 7;
        int kt = l >> 5, r32 = l & 31;
        if (col < 1024) {
          int hd = col >> 6;
          u16* base = &Qf[((((size_t)(bb * 16 + hd) * 64 + kt) << 11)) +
                          ((c8 * 32 + r32) << 3) + d7];
#pragma unroll
          for (int r = 0; r < 4; r++) base[r * 8] = f2bf(acc[m][n][r]);
        } else if (col < 1280) {
          int kv = (col - 1024) >> 6;
          u16* base = &Kf[((((size_t)(bb * 4 + kv) * 64 + kt) << 11)) +
                          ((c8 * 32 + r32) << 3) + d7];
#pragma unroll
          for (int r = 0; r < 4; r++) base[r * 8] = f2bf(acc[m][n][r]);
        } else {
          int kv = (col - 1280) >> 6;
          ushort4 pv;
          pv.x = f2bf(acc[m][n][0]); pv.y = f2bf(acc[m][n][1]);
          pv.z = f2bf(acc[m][n][2]); pv.w = f2bf(acc[m][n][3]);
          *reinterpret_cast<ushort4*>(
              &Vf[((((size_t)(bb * 4 + kv) * 64 + kt) << 11)) +
                  ((((l >> 3) & 3) * 64 + d) << 3) + (l & 7)]) = pv;
        }
      }
    }
  }
}

// ---- flash attention: swapped 32x32, HEAD-PAIR wave, 2-wave split-KV -----
// launch_bounds(128,2): 2 waves/SIMD -> all 2048 waves resident (r15 win).
__global__ __launch_bounds__(128, 2) void attn(
    const u16* __restrict__ Qf, const u16* __restrict__ Kf,
    const u16* __restrict__ Vf, const int* __restrict__ sst,
    u16* __restrict__ Obuf) {
  const int qt = 63 - blockIdx.x;               // big blocks dispatch first
  const int hp = blockIdx.y, b = blockIdx.z;
  const int h0 = hp << 1;
  const int kvh = h0 >> 2;
  const int tid = threadIdx.x;
  const int w = tid >> 6, lane = tid & 63;
  const int qi = lane & 31, hi = lane >> 5;
  const int qw = qt * 32;
  const int q = qw + qi;
  const float slope0 = __builtin_amdgcn_exp2f(-0.5f * (float)(h0 + 1));
  const float SL0 = slope0 * LOG2E;
  const float SL1 = SL0 * RSQ2;
  const float SL0x64 = 64.f * SL0, SL1x64 = 64.f * SL1;
  const float Cs = 0.125f * LOG2E;
  const u16* Qt0 = Qf + (((size_t)(b * Hh + h0) * 64 + qt) << 11);
  const u16* Qt1 = Qt0 + ((size_t)64 << 11);    // head h0+1
  const u16* Kbase = Kf + (((size_t)(b * KVh + kvh) * 64) << 11);
  const u16* Vbase = Vf + (((size_t)(b * KVh + kvh) * 64) << 11);

  bf16x8 qfA[4], qfB[4];
#pragma unroll
  for (int c = 0; c < 4; c++) {
    qfA[c] = *reinterpret_cast<const bf16x8*>(&Qt0[((2 * c + hi) * 32 + qi) * 8]);
    qfB[c] = *reinterpret_cast<const bf16x8*>(&Qt1[((2 * c + hi) * 32 + qi) * 8]);
  }

  const int start = sst[b * Ls + q];
  const int smax = __shfl(start, 31);
  const int k_begin = __shfl(start, 0) & ~31;

  float krsl[16];                               // krow * SL0 (chain A)
#pragma unroll
  for (int r = 0; r < 16; r++)
    krsl[r] = (float)((r & 3) + 8 * (r >> 2) + 4 * hi) * SL0;
  float biasA = (float)(k_begin + 32 * w - q) * SL0;  // (kk-q)*SL - m_acc
  float biasB = (float)(k_begin + 32 * w - q) * SL1;
  float mAacc = 0.f, mBacc = 0.f;
  float lA = 0.f, lB = 0.f;
  f32x16 oAlo = {}, oAhi = {}, oBlo = {}, oBhi = {};

  auto KLD = [&](int kt, u32x4* dst) {
    const u16* p = Kbase + ((size_t)kt << 11);
#pragma unroll
    for (int c = 0; c < 4; c++)
      dst[c] = *reinterpret_cast<const u32x4*>(&p[((2 * c + hi) * 32 + qi) * 8]);
  };
  auto VLD = [&](int kt, u32x4* dst) {
    const u16* p = Vbase + ((size_t)kt << 11);
#pragma unroll
    for (int j = 0; j < 4; j++) {
      int off = ((((j & 1) * 2 + hi) * 64) + (j >> 1) * 32 + qi) * 8;
      dst[j] = *reinterpret_cast<const u32x4*>(&p[off]);
    }
  };

  auto rowmax = [&](const float* t) {           // balanced tree, depth 4
    float u0 = fmaxf(t[0], t[1]), u1 = fmaxf(t[2], t[3]);
    float u2 = fmaxf(t[4], t[5]), u3 = fmaxf(t[6], t[7]);
    float u4 = fmaxf(t[8], t[9]), u5 = fmaxf(t[10], t[11]);
    float u6 = fmaxf(t[12], t[13]), u7 = fmaxf(t[14], t[15]);
    u0 = fmaxf(u0, u1); u2 = fmaxf(u2, u3);
    u4 = fmaxf(u4, u5); u6 = fmaxf(u6, u7);
    return fmaxf(fmaxf(u0, u2), fmaxf(u4, u6));
  };

  auto body = [&](int kk, u32x4* KR, u32x4* VR) {
    f32x16 aA = {}, aB = {};
    __builtin_amdgcn_s_setprio(1);
#pragma unroll
    for (int c = 0; c < 4; c++) aA = mfma32(bc(KR[c]), qfA[c], aA);
#pragma unroll
    for (int c = 0; c < 4; c++) aB = mfma32(bc(KR[c]), qfB[c], aB);
    __builtin_amdgcn_s_setprio(0);
    const int kt2 = min(kk + 64, qw) >> 5;
    KLD(kt2, KR);                               // hidden under softmax+PV

    float tA[16], tB[16];
#pragma unroll
    for (int r = 0; r < 16; r++) {
      tA[r] = fmaf(aA[r], Cs, biasA) + krsl[r];
      tB[r] = fmaf(aB[r], Cs, biasB) + krsl[r] * RSQ2;
    }
    if (!(kk >= smax && kk < qw)) {             // mask once for both heads
#pragma unroll
      for (int r = 0; r < 16; r++) {
        int j = kk + (r & 3) + 8 * (r >> 2) + 4 * hi;
        bool v = (j >= start) && (j <= q);
        tA[r] = v ? tA[r] : -3.0e38f;
        tB[r] = v ? tB[r] : -3.0e38f;
      }
    }
    {
      float mt = max_halves(rowmax(tA));
      if (!__all(mt <= 8.f)) {                  // rare defer-max rescale
        float dm = fmaxf(mt, 0.f);
        float fac = __builtin_amdgcn_exp2f(-dm);
        biasA -= dm; lA *= fac; mAacc += dm;
#pragma unroll
        for (int r = 0; r < 16; r++) { oAlo[r] *= fac; oAhi[r] *= fac; tA[r] -= dm; }
      }
    }
    {
      float mt = max_halves(rowmax(tB));
      if (!__all(mt <= 8.f)) {
        float dm = fmaxf(mt, 0.f);
        float fac = __builtin_amdgcn_exp2f(-dm);
        biasB -= dm; lB *= fac; mBacc += dm;
#pragma unroll
        for (int r = 0; r < 16; r++) { oBlo[r] *= fac; oBhi[r] *= fac; tB[r] -= dm; }
      }
    }
    float pA[16], pB[16];
#pragma unroll
    for (int r = 0; r < 16; r++) {
      pA[r] = __builtin_amdgcn_exp2f(tA[r]);
      pB[r] = __builtin_amdgcn_exp2f(tB[r]);
    }
    float tsA = 0.f, tsB = 0.f;
#pragma unroll
    for (int r = 0; r < 16; r++) { tsA += pA[r]; tsB += pB[r]; }
    lA += sum_halves(tsA);
    lB += sum_halves(tsB);

    u32 pkA[8], pkB[8];
#pragma unroll
    for (int i = 0; i < 8; i++) {
      pkA[i] = cvtpk(pA[2 * i], pA[2 * i + 1]);
      pkB[i] = cvtpk(pB[2 * i], pB[2 * i + 1]);
    }
    pls(pkA[0], pkA[2]); pls(pkA[1], pkA[3]);
    pls(pkA[4], pkA[6]); pls(pkA[5], pkA[7]);
    pls(pkB[0], pkB[2]); pls(pkB[1], pkB[3]);
    pls(pkB[4], pkB[6]); pls(pkB[5], pkB[7]);
    u32x4 fA0 = { pkA[0], pkA[1], pkA[2], pkA[3] };
    u32x4 fA1 = { pkA[4], pkA[5], pkA[6], pkA[7] };
    u32x4 fB0 = { pkB[0], pkB[1], pkB[2], pkB[3] };
    u32x4 fB1 = { pkB[4], pkB[5], pkB[6], pkB[7] };

    __builtin_amdgcn_s_setprio(1);
    oAlo = mfma32(bc(VR[0]), bc(fA0), oAlo);
    oAlo = mfma32(bc(VR[1]), bc(fA1), oAlo);
    oAhi = mfma32(bc(VR[2]), bc(fA0), oAhi);
    oAhi = mfma32(bc(VR[3]), bc(fA1), oAhi);
    oBlo = mfma32(bc(VR[0]), bc(fB0), oBlo);
    oBlo = mfma32(bc(VR[1]), bc(fB1), oBlo);
    oBhi = mfma32(bc(VR[2]), bc(fB0), oBhi);
    oBhi = mfma32(bc(VR[3]), bc(fB1), oBhi);
    __builtin_amdgcn_s_setprio(0);
    VLD(kt2, VR);                               // prefetch next V
    biasA += SL0x64; biasB += SL1x64;
  };

  u32x4 KR[4], VR[4];
  int kk = k_begin + 32 * w;
  if (kk <= qw) { KLD(kk >> 5, KR); VLD(kk >> 5, VR); }
  for (; kk <= qw; kk += 64) body(kk, KR, VR);

  // ---- cross-wave merge (wave 1 publishes, wave 0 combines + stores) ----
  __shared__ float sm[64][69];                  // 69-stride: conflict-free
  if (w == 1) {
#pragma unroll
    for (int r = 0; r < 16; r++) {
      sm[lane][r] = oAlo[r];      sm[lane][16 + r] = oAhi[r];
      sm[lane][32 + r] = oBlo[r]; sm[lane][48 + r] = oBhi[r];
    }
    sm[lane][64] = lA; sm[lane][65] = lB;
    sm[lane][66] = mAacc; sm[lane][67] = mBacc;
  }
  __syncthreads();
  if (w == 1) return;
  {
    float mA1 = sm[lane][66], mB1 = sm[lane][67];
    float MA = fmaxf(mAacc, mA1), MB = fmaxf(mBacc, mB1);
    float fa0 = __builtin_amdgcn_exp2f(mAacc - MA);
    float fa1 = __builtin_amdgcn_exp2f(mA1 - MA);
    float fb0 = __builtin_amdgcn_exp2f(mBacc - MB);
    float fb1 = __builtin_amdgcn_exp2f(mB1 - MB);
    lA = lA * fa0 + sm[lane][64] * fa1;
    lB = lB * fb0 + sm[lane][65] * fb1;
#pragma unroll
    for (int r = 0; r < 16; r++) {
      oAlo[r] = oAlo[r] * fa0 + sm[lane][r] * fa1;
      oAhi[r] = oAhi[r] * fa0 + sm[lane][16 + r] * fa1;
      oBlo[r] = oBlo[r] * fb0 + sm[lane][32 + r] * fb1;
      oBhi[r] = oBhi[r] * fb0 + sm[lane][48 + r] * fb1;
    }
  }

  const float invA = __builtin_amdgcn_rcpf(lA);
  const float invB = __builtin_amdgcn_rcpf(lB);
  const size_t orow = (size_t)(b * Ls + q) * 1024 + h0 * 64;
#pragma unroll
  for (int g = 0; g < 4; g++) {
    int d0 = g * 8 + hi * 4;
    u32x2 pa = { cvtpk(oAlo[4 * g + 0] * invA, oAlo[4 * g + 1] * invA),
                 cvtpk(oAlo[4 * g + 2] * invA, oAlo[4 * g + 3] * invA) };
    u32x2 pb = { cvtpk(oAhi[4 * g + 0] * invA, oAhi[4 * g + 1] * invA),
                 cvtpk(oAhi[4 * g + 2] * invA, oAhi[4 * g + 3] * invA) };
    *reinterpret_cast<u32x2*>(&Obuf[orow + d0]) = pa;
    *reinterpret_cast<u32x2*>(&Obuf[orow + 32 + d0]) = pb;
    u32x2 qa = { cvtpk(oBlo[4 * g + 0] * invB, oBlo[4 * g + 1] * invB),
                 cvtpk(oBlo[4 * g + 2] * invB, oBlo[4 * g + 3] * invB) };
    u32x2 qb = { cvtpk(oBhi[4 * g + 0] * invB, oBhi[4 * g + 1] * invB),
                 cvtpk(oBhi[4 * g + 2] * invB, oBhi[4 * g + 3] * invB) };
    *reinterpret_cast<u32x2*>(&Obuf[orow + 64 + d0]) = qa;
    *reinterpret_cast<u32x2*>(&Obuf[orow + 96 + d0]) = qb;
  }
}

// ---- launch ---------------------------------------------------------------
extern "C" void kernel_launch(void* const* d_in, const int* in_sizes, int n_in,
                              void* d_out, int out_size, void* d_ws, size_t ws_size,
                              hipStream_t stream) {
  const float* hs = (const float*)d_in[0];
  const int* seg = (const int*)d_in[1];
  const float* Wq = (const float*)d_in[2];
  const float* Wk = (const float*)d_in[3];
  const float* Wv = (const float*)d_in[4];
  const float* Wo = (const float*)d_in[5];
  float* out = (float*)d_out;
  char* ws = (char*)d_ws;
  // hsb 8.4M | wqkvT 3.1M | woT 2.1M | Qf 8.4M | Kf 2.1M | Vf 2.1M | sst 16K
  u16* hsb   = (u16*)(ws);
  u16* wqkvT = (u16*)(ws + 8388608);
  u16* woT   = (u16*)(ws + 11534336);
  u16* qf    = (u16*)(ws + 13631488);
  u16* kf    = (u16*)(ws + 22020096);
  u16* vf    = (u16*)(ws + 24117248);
  int* sst   = (int*)(ws + 26214400);
  u16* obuf  = hsb;   // hsb dead after GEMM1

  prep<<<dim3(6672), dim3(256), 0, stream>>>(hs, hsb, seg, sst,
                                             Wq, Wk, Wv, Wo, wqkvT, woT);
  gemm_bt<1, 512><<<dim3(12, 32), dim3(512), 0, stream>>>(
      hsb, wqkvT, nullptr, qf, kf, vf, 4096, 1536, 1024);
  attn<<<dim3(64, 8, 2), dim3(128), 0, stream>>>(qf, kf, vf, sst, obuf);
  gemm_bt<0, 256><<<dim3(8, 32), dim3(256), 0, stream>>>(
      obuf, woT, out, nullptr, nullptr, nullptr, 4096, 1024, 1024);
}

// Round 17
// 70.359 us; speedup vs baseline: 1.0829x; 1.0829x over previous
//
#include <hip/hip_runtime.h>
#include <hip/hip_bf16.h>
#include <type_traits>

#define DI __device__ __forceinline__

typedef unsigned short u16;
typedef unsigned int u32;
typedef __bf16 bf16x8 __attribute__((ext_vector_type(8)));
typedef u16 u16x8 __attribute__((ext_vector_type(8)));
typedef float f32x4 __attribute__((ext_vector_type(4)));
typedef float f32x16 __attribute__((ext_vector_type(16)));
typedef u32 u32x2 __attribute__((ext_vector_type(2)));
typedef u32 u32x4 __attribute__((ext_vector_type(4)));

constexpr int Bb = 2, Ls = 2048, Hh = 16, KVh = 4, HD = 64;
constexpr float LOG2E = 1.44269504088896f;
constexpr float RSQ2 = 0.70710678118654752f;   // slope ratio between heads

DI u16 f2bf(float f) {
  __hip_bfloat16 h = __float2bfloat16(f);
  return __builtin_bit_cast(u16, h);
}

// packed f32x2 -> bf16x2 (RNE), single VOP3 op
DI u32 cvtpk(float lo, float hi) {
  u32 r;
  asm("v_cvt_pk_bf16_f32 %0, %1, %2" : "=v"(r) : "v"(lo), "v"(hi));
  return r;
}

// a' = [a.lo | b.lo], b' = [a.hi | b.hi].  "&" early-clobber on b forces
// DISTINCT registers (r12 NaN landmine: equal-valued a,b coalesced into one
// reg -> swap(v0,v0) garbage).
DI void pls(u32& a, u32& b) {
  asm("v_permlane32_swap_b32 %0, %1" : "+v"(a), "+&v"(b));
}
DI float sum_halves(float v) {        // v[l] + v[l^32], valid in all lanes
  u32 a = __builtin_bit_cast(u32, v), b = a;
  pls(a, b);
  return __builtin_bit_cast(float, a) + __builtin_bit_cast(float, b);
}
DI float max_halves(float v) {
  u32 a = __builtin_bit_cast(u32, v), b = a;
  pls(a, b);
  return fmaxf(__builtin_bit_cast(float, a), __builtin_bit_cast(float, b));
}

DI f32x4 mfma16(bf16x8 a, bf16x8 b, f32x4 c) {
  return __builtin_amdgcn_mfma_f32_16x16x32_bf16(a, b, c, 0, 0, 0);
}
DI f32x16 mfma32(bf16x8 a, bf16x8 b, f32x16 c) {
  return __builtin_amdgcn_mfma_f32_32x32x16_bf16(a, b, c, 0, 0, 0);
}
DI bf16x8 bc(u32x4 v) { return __builtin_bit_cast(bf16x8, v); }

// async global->LDS, 16B per lane; LDS dest = wave-uniform base + lane*16
DI void gld16(const u16* g, u16* l) {
  __builtin_amdgcn_global_load_lds(
      (const __attribute__((address_space(1))) u32*)g,
      (__attribute__((address_space(3))) u32*)l, 16, 0, 0);
}

// ---- fused prep: hs cvt + seg starts + all 4 weight transposes -----------
__global__ void prep(const float* __restrict__ hs, u16* __restrict__ hsb,
                     const int* __restrict__ seg, int* __restrict__ sst,
                     const float* __restrict__ Wq, const float* __restrict__ Wk,
                     const float* __restrict__ Wv, const float* __restrict__ Wo,
                     u16* __restrict__ wqkvT, u16* __restrict__ woT) {
  int bid = blockIdx.x;
  if (bid < 4096) {
    int i = bid * 256 + threadIdx.x;
    float4 v = reinterpret_cast<const float4*>(hs)[i];
    ushort4 o;
    o.x = f2bf(v.x); o.y = f2bf(v.y); o.z = f2bf(v.z); o.w = f2bf(v.w);
    reinterpret_cast<ushort4*>(hsb)[i] = o;
    return;
  }
  if (bid < 4112) {
    int idx = bid - 4096;
    int b = idx >> 3;
    int l = (idx & 7) * 256 + threadIdx.x;
    const int* s = seg + b * Ls;
    int v = s[l];
    int lo = 0, hi = l;
    while (lo < hi) {
      int mid = (lo + hi) >> 1;
      if (s[mid] < v) lo = mid + 1; else hi = mid;
    }
    sst[b * Ls + l] = lo;
    return;
  }
  int t = bid - 4112;
  const float* in; u16* out; int N, rowoff, x, y;
  if (t < 1024)      { in = Wq; out = wqkvT; N = 1024; rowoff = 0;
                       x = t & 31; y = t >> 5; }
  else if (t < 1280) { in = Wk; out = wqkvT; N = 256; rowoff = 1024;
                       int u = t - 1024; x = u & 7; y = u >> 3; }
  else if (t < 1536) { in = Wv; out = wqkvT; N = 256; rowoff = 1280;
                       int u = t - 1280; x = u & 7; y = u >> 3; }
  else               { in = Wo; out = woT; N = 1024; rowoff = 0;
                       int u = t - 1536; x = u & 31; y = u >> 5; }
  __shared__ u16 tl[32][33];
  int k0 = y * 32, n0 = x * 32;
  int tx = threadIdx.x & 31, ty = threadIdx.x >> 5;
#pragma unroll
  for (int i = ty; i < 32; i += 8)
    tl[i][tx] = f2bf(in[(size_t)(k0 + i) * N + n0 + tx]);
  __syncthreads();
#pragma unroll
  for (int i = ty; i < 32; i += 8)
    out[(size_t)(rowoff + n0 + i) * 1024 + k0 + tx] = tl[tx][i];
}

// ---- GEMM: 8-wave 128x128, 4-buffer rotation, 1 barrier/K-step -----------
// XCD-aware chunked block swizzle (T1): consecutive linear tile ids ->
// same XCD L2 (grids are multiples of 8 -> bijective).
// Hardened barrier: lgkmcnt(0)+sched_barrier(0) before s_barrier (rule-18).
// LDS XOR swizzle both-sides (r11). Requires K % 128 == 0.
template <int MODE>
__global__ __launch_bounds__(512) void gemm_bt(
    const u16* __restrict__ A, const u16* __restrict__ Bt,
    float* __restrict__ C, u16* __restrict__ Qf, u16* __restrict__ Kf,
    u16* __restrict__ Vf, int M, int N, int K) {
  __shared__ u16 lA[4][128 * 32];
  __shared__ u16 lB[4][128 * 32];
  const int id = blockIdx.y * gridDim.x + blockIdx.x;
  const int cpx = (gridDim.x * gridDim.y) >> 3;
  const int swz = (id & 7) * cpx + (id >> 3);
  const int m0 = (swz / gridDim.x) * 128, n0 = (swz % gridDim.x) * 128;
  const int tid = threadIdx.x;
  const int lane = tid & 63;
  const int wr = ((tid >> 8) & 1) * 64;         // wm = w>>2
  const int wc = ((tid >> 6) & 3) * 32;         // wn = w&3
  const int lr = lane & 15;
  const int lk = (((lane >> 4) ^ (lane & 3)) * 8);     // swizzled read slot
  const int r0 = tid >> 2;
  const int c0 = (((tid & 3) ^ ((tid >> 2) & 3)) * 8); // swizzled src group
  const int woff = (tid & 0x1C0) << 4;          // wave-uniform LDS byte base
  const u16* pA0 = &A[(size_t)(m0 + r0) * K + c0];
  const u16* pB0 = &Bt[(size_t)(n0 + r0) * K + c0];

  auto stage = [&](u16* sA, u16* sB, int k0) {
    gld16(pA0 + k0, (u16*)((char*)sA + woff));
    gld16(pB0 + k0, (u16*)((char*)sB + woff));
  };

  f32x4 acc[4][2] = {};
  auto compute = [&](const u16* sA, const u16* sB) {
    bf16x8 af[4], bfv[2];
#pragma unroll
    for (int m = 0; m < 4; m++)
      af[m] = *reinterpret_cast<const bf16x8*>(&sA[(wr + m * 16 + lr) * 32 + lk]);
#pragma unroll
    for (int n = 0; n < 2; n++)
      bfv[n] = *reinterpret_cast<const bf16x8*>(&sB[(wc + n * 16 + lr) * 32 + lk]);
#pragma unroll
    for (int m = 0; m < 4; m++)
#pragma unroll
      for (int n = 0; n < 2; n++)
        acc[m][n] = mfma16(af[m], bfv[n], acc[m][n]);
  };

#define BODY(B, VM, KC, DOST)                                        \
  do {                                                               \
    asm volatile("s_waitcnt lgkmcnt(0)" ::: "memory");               \
    __builtin_amdgcn_sched_barrier(0);                               \
    asm volatile("s_waitcnt vmcnt(" VM ")" ::: "memory");            \
    __builtin_amdgcn_s_barrier();                                    \
    asm volatile("" ::: "memory");                                   \
    if (DOST) stage(lA[(B + 3) & 3], lB[(B + 3) & 3], (KC) + 96);    \
    compute(lA[B], lB[B]);                                           \
  } while (0)

  stage(lA[0], lB[0], 0);
  stage(lA[1], lB[1], 32);
  stage(lA[2], lB[2], 64);
  int k0 = 0;
  for (; k0 + 224 <= K; k0 += 128) {            // full groups, all stage
    BODY(0, "4", k0, 1);
    BODY(1, "4", k0 + 32, 1);
    BODY(2, "4", k0 + 64, 1);
    BODY(3, "4", k0 + 96, 1);
  }
  BODY(0, "4", k0, 1);                          // stages K-32
  BODY(1, "4", k0 + 32, 0);
  BODY(2, "2", k0 + 64, 0);
  BODY(3, "0", k0 + 96, 0);
#undef BODY

  const int rr = (lane >> 4) * 4, cc = lane & 15;
#pragma unroll
  for (int m = 0; m < 4; m++) {
    int row0 = m0 + wr + m * 16 + rr;
#pragma unroll
    for (int n = 0; n < 2; n++) {
      int col = n0 + wc + n * 16 + cc;
      if constexpr (MODE == 0) {
#pragma unroll
        for (int r = 0; r < 4; r++)
          C[(size_t)(row0 + r) * N + col] = acc[m][n][r];
      } else {
        int bb = row0 >> 11, l = row0 & 2047;
        int d = col & 63, c8 = d >> 3, d7 = d & 7;
        int kt = l >> 5, r32 = l & 31;
        if (col < 1024) {
          int hd = col >> 6;
          u16* base = &Qf[((((size_t)(bb * 16 + hd) * 64 + kt) << 11)) +
                          ((c8 * 32 + r32) << 3) + d7];
#pragma unroll
          for (int r = 0; r < 4; r++) base[r * 8] = f2bf(acc[m][n][r]);
        } else if (col < 1280) {
          int kv = (col - 1024) >> 6;
          u16* base = &Kf[((((size_t)(bb * 4 + kv) * 64 + kt) << 11)) +
                          ((c8 * 32 + r32) << 3) + d7];
#pragma unroll
          for (int r = 0; r < 4; r++) base[r * 8] = f2bf(acc[m][n][r]);
        } else {
          int kv = (col - 1280) >> 6;
          ushort4 pv;
          pv.x = f2bf(acc[m][n][0]); pv.y = f2bf(acc[m][n][1]);
          pv.z = f2bf(acc[m][n][2]); pv.w = f2bf(acc[m][n][3]);
          *reinterpret_cast<ushort4*>(
              &Vf[((((size_t)(bb * 4 + kv) * 64 + kt) << 11)) +
                  ((((l >> 3) & 3) * 64 + d) << 3) + (l & 7)]) = pv;
        }
      }
    }
  }
}

// ---- flash attention: swapped 32x32, HEAD-PAIR wave, 2-wave split-KV -----
// launch_bounds(128,2): 2 waves/SIMD -> all 2048 waves resident (r15 win).
__global__ __launch_bounds__(128, 2) void attn(
    const u16* __restrict__ Qf, const u16* __restrict__ Kf,
    const u16* __restrict__ Vf, const int* __restrict__ sst,
    u16* __restrict__ Obuf) {
  const int qt = 63 - blockIdx.x;               // big blocks dispatch first
  const int hp = blockIdx.y, b = blockIdx.z;
  const int h0 = hp << 1;
  const int kvh = h0 >> 2;
  const int tid = threadIdx.x;
  const int w = tid >> 6, lane = tid & 63;
  const int qi = lane & 31, hi = lane >> 5;
  const int qw = qt * 32;
  const int q = qw + qi;
  const float slope0 = __builtin_amdgcn_exp2f(-0.5f * (float)(h0 + 1));
  const float SL0 = slope0 * LOG2E;
  const float SL1 = SL0 * RSQ2;
  const float SL0x64 = 64.f * SL0, SL1x64 = 64.f * SL1;
  const float Cs = 0.125f * LOG2E;
  const u16* Qt0 = Qf + (((size_t)(b * Hh + h0) * 64 + qt) << 11);
  const u16* Qt1 = Qt0 + ((size_t)64 << 11);    // head h0+1
  const u16* Kbase = Kf + (((size_t)(b * KVh + kvh) * 64) << 11);
  const u16* Vbase = Vf + (((size_t)(b * KVh + kvh) * 64) << 11);

  bf16x8 qfA[4], qfB[4];
#pragma unroll
  for (int c = 0; c < 4; c++) {
    qfA[c] = *reinterpret_cast<const bf16x8*>(&Qt0[((2 * c + hi) * 32 + qi) * 8]);
    qfB[c] = *reinterpret_cast<const bf16x8*>(&Qt1[((2 * c + hi) * 32 + qi) * 8]);
  }

  const int start = sst[b * Ls + q];
  const int smax = __shfl(start, 31);
  const int k_begin = __shfl(start, 0) & ~31;

  float krsl[16];                               // krow * SL0 (chain A)
#pragma unroll
  for (int r = 0; r < 16; r++)
    krsl[r] = (float)((r & 3) + 8 * (r >> 2) + 4 * hi) * SL0;
  float biasA = (float)(k_begin + 32 * w - q) * SL0;  // (kk-q)*SL - m_acc
  float biasB = (float)(k_begin + 32 * w - q) * SL1;
  float mAacc = 0.f, mBacc = 0.f;
  float lA = 0.f, lB = 0.f;
  f32x16 oAlo = {}, oAhi = {}, oBlo = {}, oBhi = {};

  auto KLD = [&](int kt, u32x4* dst) {
    const u16* p = Kbase + ((size_t)kt << 11);
#pragma unroll
    for (int c = 0; c < 4; c++)
      dst[c] = *reinterpret_cast<const u32x4*>(&p[((2 * c + hi) * 32 + qi) * 8]);
  };
  auto VLD = [&](int kt, u32x4* dst) {
    const u16* p = Vbase + ((size_t)kt << 11);
#pragma unroll
    for (int j = 0; j < 4; j++) {
      int off = ((((j & 1) * 2 + hi) * 64) + (j >> 1) * 32 + qi) * 8;
      dst[j] = *reinterpret_cast<const u32x4*>(&p[off]);
    }
  };

  auto rowmax = [&](const float* t) {           // balanced tree, depth 4
    float u0 = fmaxf(t[0], t[1]), u1 = fmaxf(t[2], t[3]);
    float u2 = fmaxf(t[4], t[5]), u3 = fmaxf(t[6], t[7]);
    float u4 = fmaxf(t[8], t[9]), u5 = fmaxf(t[10], t[11]);
    float u6 = fmaxf(t[12], t[13]), u7 = fmaxf(t[14], t[15]);
    u0 = fmaxf(u0, u1); u2 = fmaxf(u2, u3);
    u4 = fmaxf(u4, u5); u6 = fmaxf(u6, u7);
    return fmaxf(fmaxf(u0, u2), fmaxf(u4, u6));
  };

  auto body = [&](int kk, u32x4* KR, u32x4* VR) {
    f32x16 aA = {}, aB = {};
    __builtin_amdgcn_s_setprio(1);
#pragma unroll
    for (int c = 0; c < 4; c++) aA = mfma32(bc(KR[c]), qfA[c], aA);
#pragma unroll
    for (int c = 0; c < 4; c++) aB = mfma32(bc(KR[c]), qfB[c], aB);
    __builtin_amdgcn_s_setprio(0);
    const int kt2 = min(kk + 64, qw) >> 5;
    KLD(kt2, KR);                               // hidden under softmax+PV

    float tA[16], tB[16];
#pragma unroll
    for (int r = 0; r < 16; r++) {
      tA[r] = fmaf(aA[r], Cs, biasA) + krsl[r];
      tB[r] = fmaf(aB[r], Cs, biasB) + krsl[r] * RSQ2;
    }
    if (!(kk >= smax && kk < qw)) {             // mask once for both heads
#pragma unroll
      for (int r = 0; r < 16; r++) {
        int j = kk + (r & 3) + 8 * (r >> 2) + 4 * hi;
        bool v = (j >= start) && (j <= q);
        tA[r] = v ? tA[r] : -3.0e38f;
        tB[r] = v ? tB[r] : -3.0e38f;
      }
    }
    {
      float mt = max_halves(rowmax(tA));
      if (!__all(mt <= 8.f)) {                  // rare defer-max rescale
        float dm = fmaxf(mt, 0.f);
        float fac = __builtin_amdgcn_exp2f(-dm);
        biasA -= dm; lA *= fac; mAacc += dm;
#pragma unroll
        for (int r = 0; r < 16; r++) { oAlo[r] *= fac; oAhi[r] *= fac; tA[r] -= dm; }
      }
    }
    {
      float mt = max_halves(rowmax(tB));
      if (!__all(mt <= 8.f)) {
        float dm = fmaxf(mt, 0.f);
        float fac = __builtin_amdgcn_exp2f(-dm);
        biasB -= dm; lB *= fac; mBacc += dm;
#pragma unroll
        for (int r = 0; r < 16; r++) { oBlo[r] *= fac; oBhi[r] *= fac; tB[r] -= dm; }
      }
    }
    float pA[16], pB[16];
#pragma unroll
    for (int r = 0; r < 16; r++) {
      pA[r] = __builtin_amdgcn_exp2f(tA[r]);
      pB[r] = __builtin_amdgcn_exp2f(tB[r]);
    }
    float tsA = 0.f, tsB = 0.f;
#pragma unroll
    for (int r = 0; r < 16; r++) { tsA += pA[r]; tsB += pB[r]; }
    lA += sum_halves(tsA);
    lB += sum_halves(tsB);

    u32 pkA[8], pkB[8];
#pragma unroll
    for (int i = 0; i < 8; i++) {
      pkA[i] = cvtpk(pA[2 * i], pA[2 * i + 1]);
      pkB[i] = cvtpk(pB[2 * i], pB[2 * i + 1]);
    }
    pls(pkA[0], pkA[2]); pls(pkA[1], pkA[3]);
    pls(pkA[4], pkA[6]); pls(pkA[5], pkA[7]);
    pls(pkB[0], pkB[2]); pls(pkB[1], pkB[3]);
    pls(pkB[4], pkB[6]); pls(pkB[5], pkB[7]);
    u32x4 fA0 = { pkA[0], pkA[1], pkA[2], pkA[3] };
    u32x4 fA1 = { pkA[4], pkA[5], pkA[6], pkA[7] };
    u32x4 fB0 = { pkB[0], pkB[1], pkB[2], pkB[3] };
    u32x4 fB1 = { pkB[4], pkB[5], pkB[6], pkB[7] };

    __builtin_amdgcn_s_setprio(1);
    oAlo = mfma32(bc(VR[0]), bc(fA0), oAlo);
    oAlo = mfma32(bc(VR[1]), bc(fA1), oAlo);
    oAhi = mfma32(bc(VR[2]), bc(fA0), oAhi);
    oAhi = mfma32(bc(VR[3]), bc(fA1), oAhi);
    oBlo = mfma32(bc(VR[0]), bc(fB0), oBlo);
    oBlo = mfma32(bc(VR[1]), bc(fB1), oBlo);
    oBhi = mfma32(bc(VR[2]), bc(fB0), oBhi);
    oBhi = mfma32(bc(VR[3]), bc(fB1), oBhi);
    __builtin_amdgcn_s_setprio(0);
    VLD(kt2, VR);                               // prefetch next V
    biasA += SL0x64; biasB += SL1x64;
  };

  u32x4 KR[4], VR[4];
  int kk = k_begin + 32 * w;
  if (kk <= qw) { KLD(kk >> 5, KR); VLD(kk >> 5, VR); }
  for (; kk <= qw; kk += 64) body(kk, KR, VR);

  // ---- cross-wave merge (wave 1 publishes, wave 0 combines + stores) ----
  __shared__ float sm[64][69];                  // 69-stride: conflict-free
  if (w == 1) {
#pragma unroll
    for (int r = 0; r < 16; r++) {
      sm[lane][r] = oAlo[r];      sm[lane][16 + r] = oAhi[r];
      sm[lane][32 + r] = oBlo[r]; sm[lane][48 + r] = oBhi[r];
    }
    sm[lane][64] = lA; sm[lane][65] = lB;
    sm[lane][66] = mAacc; sm[lane][67] = mBacc;
  }
  __syncthreads();
  if (w == 1) return;
  {
    float mA1 = sm[lane][66], mB1 = sm[lane][67];
    float MA = fmaxf(mAacc, mA1), MB = fmaxf(mBacc, mB1);
    float fa0 = __builtin_amdgcn_exp2f(mAacc - MA);
    float fa1 = __builtin_amdgcn_exp2f(mA1 - MA);
    float fb0 = __builtin_amdgcn_exp2f(mBacc - MB);
    float fb1 = __builtin_amdgcn_exp2f(mB1 - MB);
    lA = lA * fa0 + sm[lane][64] * fa1;
    lB = lB * fb0 + sm[lane][65] * fb1;
#pragma unroll
    for (int r = 0; r < 16; r++) {
      oAlo[r] = oAlo[r] * fa0 + sm[lane][r] * fa1;
      oAhi[r] = oAhi[r] * fa0 + sm[lane][16 + r] * fa1;
      oBlo[r] = oBlo[r] * fb0 + sm[lane][32 + r] * fb1;
      oBhi[r] = oBhi[r] * fb0 + sm[lane][48 + r] * fb1;
    }
  }

  const float invA = __builtin_amdgcn_rcpf(lA);
  const float invB = __builtin_amdgcn_rcpf(lB);
  const size_t orow = (size_t)(b * Ls + q) * 1024 + h0 * 64;
#pragma unroll
  for (int g = 0; g < 4; g++) {
    int d0 = g * 8 + hi * 4;
    u32x2 pa = { cvtpk(oAlo[4 * g + 0] * invA, oAlo[4 * g + 1] * invA),
                 cvtpk(oAlo[4 * g + 2] * invA, oAlo[4 * g + 3] * invA) };
    u32x2 pb = { cvtpk(oAhi[4 * g + 0] * invA, oAhi[4 * g + 1] * invA),
                 cvtpk(oAhi[4 * g + 2] * invA, oAhi[4 * g + 3] * invA) };
    *reinterpret_cast<u32x2*>(&Obuf[orow + d0]) = pa;
    *reinterpret_cast<u32x2*>(&Obuf[orow + 32 + d0]) = pb;
    u32x2 qa = { cvtpk(oBlo[4 * g + 0] * invB, oBlo[4 * g + 1] * invB),
                 cvtpk(oBlo[4 * g + 2] * invB, oBlo[4 * g + 3] * invB) };
    u32x2 qb = { cvtpk(oBhi[4 * g + 0] * invB, oBhi[4 * g + 1] * invB),
                 cvtpk(oBhi[4 * g + 2] * invB, oBhi[4 * g + 3] * invB) };
    *reinterpret_cast<u32x2*>(&Obuf[orow + 64 + d0]) = qa;
    *reinterpret_cast<u32x2*>(&Obuf[orow + 96 + d0]) = qb;
  }
}

// ---- launch ---------------------------------------------------------------
extern "C" void kernel_launch(void* const* d_in, const int* in_sizes, int n_in,
                              void* d_out, int out_size, void* d_ws, size_t ws_size,
                              hipStream_t stream) {
  const float* hs = (const float*)d_in[0];
  const int* seg = (const int*)d_in[1];
  const float* Wq = (const float*)d_in[2];
  const float* Wk = (const float*)d_in[3];
  const float* Wv = (const float*)d_in[4];
  const float* Wo = (const float*)d_in[5];
  float* out = (float*)d_out;
  char* ws = (char*)d_ws;
  // hsb 8.4M | wqkvT 3.1M | woT 2.1M | Qf 8.4M | Kf 2.1M | Vf 2.1M | sst 16K
  u16* hsb   = (u16*)(ws);
  u16* wqkvT = (u16*)(ws + 8388608);
  u16* woT   = (u16*)(ws + 11534336);
  u16* qf    = (u16*)(ws + 13631488);
  u16* kf    = (u16*)(ws + 22020096);
  u16* vf    = (u16*)(ws + 24117248);
  int* sst   = (int*)(ws + 26214400);
  u16* obuf  = hsb;   // hsb dead after GEMM1

  prep<<<dim3(6672), dim3(256), 0, stream>>>(hs, hsb, seg, sst,
                                             Wq, Wk, Wv, Wo, wqkvT, woT);
  gemm_bt<1><<<dim3(12, 32), dim3(512), 0, stream>>>(
      hsb, wqkvT, nullptr, qf, kf, vf, 4096, 1536, 1024);
  attn<<<dim3(64, 8, 2), dim3(128), 0, stream>>>(qf, kf, vf, sst, obuf);
  gemm_bt<0><<<dim3(8, 32), dim3(512), 0, stream>>>(
      obuf, woT, out, nullptr, nullptr, nullptr, 4096, 1024, 1024);
}